// Round 1
// baseline (361.761 us; speedup 1.0000x reference)
//
#include <hip/hip_runtime.h>

typedef _Float16 f16;
typedef _Float16 f16x4 __attribute__((ext_vector_type(4)));
typedef _Float16 f16x8 __attribute__((ext_vector_type(8)));
typedef float f32x4 __attribute__((ext_vector_type(4)));

#define TM 32
#define NATOMS 65536

// ---------------- workspace layout ----------------
// [0,64)           : counts[4] (zeroed via hipMemsetAsync)
// [256, 256+1MB)   : lists[4][65536] int
// [1049600, ...)   : fp16 transposed/padded weights, 310208 elems (620 KB)
#define WS_LISTS_OFF 256
#define WS_W_OFF 1049600
#define WS_NEEDED (WS_W_OFF + 310208 * 2)

struct ConvJob { const float* src; int K, N, Kpad, Npad, start; };
struct ConvParams { ConvJob jobs[16]; int total; f16* base; };

struct MlpParams {
  const float* aev;
  const float* b0;
  const float* b1;
  const float* bias[4][4];   // original fp32 biases per species/layer
  const f16*   w[4][4];      // transposed padded fp16 weights [Npad][Kpad]
  const int*   counts;
  const int*   lists;
  float*       out;
  int Kpad1[4];              // layer1 K (padded) = {160,160,128,128}
  int Nt0[4];                // layer0 n-tiles = {10,10,8,8}
  int Nreal0[4];             // {160,144,128,128}
  int Nreal1[4];             // {128,112,112,112}
};

// ---------------- routing: compact atom indices per species ----------------
__global__ void route_kernel(const int* __restrict__ species, int* counts, int* lists) {
  int i = blockIdx.x * blockDim.x + threadIdx.x;
  int s = species[i];
  int lane = threadIdx.x & 63;
  #pragma unroll
  for (int t = 0; t < 4; t++) {
    unsigned long long mask = __ballot(s == t);
    if (s == t) {
      int leader = __ffsll(mask) - 1;
      int rank = __popcll(mask & ((1ull << lane) - 1ull));
      int base = 0;
      if (lane == leader) base = atomicAdd(&counts[t], __popcll(mask));
      base = __shfl(base, leader, 64);
      lists[t * NATOMS + base + rank] = i;
    }
  }
}

// ---------------- weight fp32 -> fp16, transpose to [Npad][Kpad], zero-pad ----
__global__ void convert_kernel(ConvParams p) {
  int gid = blockIdx.x * blockDim.x + threadIdx.x;
  if (gid >= p.total) return;
  int j = 0;
  #pragma unroll
  for (int i = 1; i < 16; i++)
    if (gid >= p.jobs[i].start) j = i;
  ConvJob jb = p.jobs[j];
  int e = gid - jb.start;
  int n = e / jb.Kpad;
  int k = e - n * jb.Kpad;
  float v = (n < jb.N && k < jb.K) ? jb.src[k * jb.N + n] : 0.f;
  p.base[gid] = (f16)v;
}

// ---------------- one MFMA GEMM layer: dst = act(src @ W + b) ----------------
// A frag: m = lane&15 (within wave's 16-row slice), k = (lane>>4)*8 + j
// B frag: n = lane&15, k = (lane>>4)*8 + j   (W stored [n][k] -> contiguous 16B)
// C/D   : col n = lane&15, row m = (lane>>4)*4 + r
template <bool ACT>
__device__ __forceinline__ void layer(const f16* src, int ss, f16* dst, int ds,
                                      const f16* __restrict__ Wt,
                                      const float* __restrict__ bias,
                                      int Kpad, int Ntiles, int Nreal,
                                      int wave, int lane) {
  int q = lane >> 4, nlo = lane & 15;
  int mbase = (wave & 1) * 16;
  const f16* arow = src + (mbase + nlo) * ss + q * 8;
  for (int nt = (wave >> 1); nt < Ntiles; nt += 2) {
    f32x4 acc = {0.f, 0.f, 0.f, 0.f};
    const f16* brow = Wt + (nt * 16 + nlo) * Kpad + q * 8;
    for (int k = 0; k < Kpad; k += 32) {
      f16x8 a = *(const f16x8*)(arow + k);
      f16x8 b = *(const f16x8*)(brow + k);
      acc = __builtin_amdgcn_mfma_f32_16x16x32_f16(a, b, acc, 0, 0, 0);
    }
    int n = nt * 16 + nlo;
    float bv = (n < Nreal) ? bias[n] : 0.f;
    #pragma unroll
    for (int r = 0; r < 4; r++) {
      float v = acc[r] + bv;
      if (ACT) v = v > 0.f ? v : 0.1f * (__expf(v * 10.f) - 1.f);
      dst[(mbase + q * 4 + r) * ds + n] = (f16)v;
    }
  }
}

// ---------------- fused routed MLP, 32 atoms per block ----------------
__global__ __launch_bounds__(256) void mlp_kernel(MlpParams p) {
  int s = blockIdx.y;
  int cnt = p.counts[s];
  int tile = blockIdx.x;
  if (tile * TM >= cnt) return;
  int valid = min(TM, cnt - tile * TM);
  const int* list = p.lists + s * NATOMS + tile * TM;

  __shared__ f16 X[TM][392];    // 384 + 8 pad (16B-aligned rows)
  __shared__ f16 Bf0[TM][168];  // up to 160 cols
  __shared__ f16 Bf1[TM][136];  // up to 128 cols
  __shared__ int idxs[TM];

  int t = threadIdx.x;
  if (t < TM) idxs[t] = (t < valid) ? list[t] : -1;

  // gather: 8 threads per atom row, fp32 -> fp16 into LDS
  {
    int row = t >> 3, l8 = t & 7;
    int atom = (row < valid) ? list[row] : -1;
    const float* srcp = p.aev + (size_t)(atom < 0 ? 0 : atom) * 384;
    #pragma unroll
    for (int i = 0; i < 12; i++) {
      int c4 = l8 + i * 8;
      float4 v = make_float4(0.f, 0.f, 0.f, 0.f);
      if (atom >= 0) v = *(const float4*)(srcp + c4 * 4);
      f16x4 h = {(f16)v.x, (f16)v.y, (f16)v.z, (f16)v.w};
      *(f16x4*)(&X[row][c4 * 4]) = h;
    }
  }
  __syncthreads();

  int wave = t >> 6, lane = t & 63;

  layer<true>(&X[0][0], 392, &Bf0[0][0], 168, p.w[s][0], p.bias[s][0],
              384, p.Nt0[s], p.Nreal0[s], wave, lane);
  __syncthreads();
  layer<true>(&Bf0[0][0], 168, &Bf1[0][0], 136, p.w[s][1], p.bias[s][1],
              p.Kpad1[s], 8, p.Nreal1[s], wave, lane);
  __syncthreads();
  layer<true>(&Bf1[0][0], 136, &Bf0[0][0], 168, p.w[s][2], p.bias[s][2],
              128, 6, 96, wave, lane);
  __syncthreads();

  // layer 3: K=96, N=1 (W padded to 16 cols, only col 0 nonzero)
  if ((wave >> 1) == 0) {
    int q = lane >> 4, nlo = lane & 15;
    int mbase = (wave & 1) * 16;
    const f16* arow = &Bf0[0][0] + (mbase + nlo) * 168 + q * 8;
    const f16* brow = p.w[s][3] + nlo * 96 + q * 8;
    f32x4 acc = {0.f, 0.f, 0.f, 0.f};
    #pragma unroll
    for (int k = 0; k < 96; k += 32) {
      f16x8 a = *(const f16x8*)(arow + k);
      f16x8 b = *(const f16x8*)(brow + k);
      acc = __builtin_amdgcn_mfma_f32_16x16x32_f16(a, b, acc, 0, 0, 0);
    }
    if (nlo == 0) {
      float b3 = p.bias[s][3][0];
      float b0v = p.b0[s], b1v = p.b1[s];
      #pragma unroll
      for (int r = 0; r < 4; r++) {
        int m = mbase + q * 4 + r;
        if (m < valid) {
          float coef = acc[r] + b3;
          p.out[idxs[m]] = b0v + b1v * coef;
        }
      }
    }
  }
}

extern "C" void kernel_launch(void* const* d_in, const int* in_sizes, int n_in,
                              void* d_out, int out_size, void* d_ws, size_t ws_size,
                              hipStream_t stream) {
  if (ws_size < WS_NEEDED) return;  // workspace too small — fail loud

  const int* species = (const int*)d_in[0];
  const float* aev = (const float*)d_in[1];
  const float* b0 = (const float*)d_in[2];
  const float* b1 = (const float*)d_in[3];

  static const int F1[4]  = {160, 144, 128, 128};
  static const int F1p[4] = {160, 160, 128, 128};
  static const int F2[4]  = {128, 112, 112, 112};

  char* wsb = (char*)d_ws;
  int* counts = (int*)wsb;
  int* lists = (int*)(wsb + WS_LISTS_OFF);
  f16* wbase = (f16*)(wsb + WS_W_OFF);

  ConvParams cp;
  MlpParams mp;
  mp.aev = aev; mp.b0 = b0; mp.b1 = b1;
  mp.counts = counts; mp.lists = lists; mp.out = (float*)d_out;

  int off = 0, ji = 0;
  for (int s = 0; s < 4; s++) {
    int dims[5] = {384, F1[s], F2[s], 96, 1};
    int Kp[4] = {384, F1p[s], 128, 96};
    int Np[4] = {F1p[s], 128, 96, 16};
    for (int l = 0; l < 4; l++) {
      const float* w = (const float*)d_in[4 + s * 8 + l * 2];
      const float* b = (const float*)d_in[4 + s * 8 + l * 2 + 1];
      cp.jobs[ji].src = w;
      cp.jobs[ji].K = dims[l];
      cp.jobs[ji].N = dims[l + 1];
      cp.jobs[ji].Kpad = Kp[l];
      cp.jobs[ji].Npad = Np[l];
      cp.jobs[ji].start = off;
      mp.w[s][l] = wbase + off;
      mp.bias[s][l] = b;
      off += Kp[l] * Np[l];
      ji++;
    }
    mp.Kpad1[s] = F1p[s];
    mp.Nt0[s] = F1p[s] / 16;
    mp.Nreal0[s] = F1[s];
    mp.Nreal1[s] = F2[s];
  }
  cp.total = off;
  cp.base = wbase;

  hipMemsetAsync(d_ws, 0, 64, stream);
  route_kernel<<<NATOMS / 256, 256, 0, stream>>>(species, counts, lists);
  convert_kernel<<<(off + 255) / 256, 256, 0, stream>>>(cp);
  mlp_kernel<<<dim3(2048, 4), 256, 0, stream>>>(mp);
}

// Round 2
// 314.525 us; speedup vs baseline: 1.1502x; 1.1502x over previous
//
#include <hip/hip_runtime.h>

typedef _Float16 f16;
typedef _Float16 f16x4 __attribute__((ext_vector_type(4)));
typedef _Float16 f16x8 __attribute__((ext_vector_type(8)));
typedef float f32x4 __attribute__((ext_vector_type(4)));

#define TM 32
#define NATOMS 65536

// ---------------- workspace layout ----------------
// [0,64)           : counts[4] (zeroed via hipMemsetAsync)
// [256, 256+1MB)   : lists[4][65536] int
// [1049600, ...)   : fp16 transposed/padded weights, 310208 elems (620 KB)
#define WS_LISTS_OFF 256
#define WS_W_OFF 1049600
#define WS_NEEDED (WS_W_OFF + 310208 * 2)

struct ConvJob { const float* src; int K, N, Kpad, Npad, start; };
struct ConvParams { ConvJob jobs[16]; int total; f16* base; };

struct MlpParams {
  const float* aev;
  const float* b0;
  const float* b1;
  const float* bias[4][4];   // original fp32 biases per species/layer
  const f16*   w[4][4];      // transposed padded fp16 weights [Npad][Kpad]
  const int*   counts;
  const int*   lists;
  float*       out;
  int Nreal0[4];             // {160,144,128,128}
  int Nreal1[4];             // {128,112,112,112}
};

// ---------------- routing: one atomic per species per block ----------------
__global__ void route_kernel(const int* __restrict__ species, int* counts, int* lists) {
  __shared__ int wcnt[4][4];    // [wave][species]
  __shared__ int wbase[4][4];
  int i = blockIdx.x * 256 + threadIdx.x;
  int s = species[i];
  int wave = threadIdx.x >> 6, lane = threadIdx.x & 63;
  unsigned long long m[4];
  #pragma unroll
  for (int t = 0; t < 4; t++) {
    m[t] = __ballot(s == t);
    if (lane == 0) wcnt[wave][t] = __popcll(m[t]);
  }
  __syncthreads();
  if (threadIdx.x < 4) {
    int t = threadIdx.x;
    int c0 = wcnt[0][t], c1 = wcnt[1][t], c2 = wcnt[2][t], c3 = wcnt[3][t];
    int base = atomicAdd(&counts[t], c0 + c1 + c2 + c3);
    wbase[0][t] = base;
    wbase[1][t] = base + c0;
    wbase[2][t] = base + c0 + c1;
    wbase[3][t] = base + c0 + c1 + c2;
  }
  __syncthreads();
  int rnk = __popcll(m[s] & ((1ull << lane) - 1ull));
  lists[s * NATOMS + wbase[wave][s] + rnk] = i;
}

// ---------------- weight fp32 -> fp16, transpose to [Npad][Kpad], zero-pad ----
__global__ void convert_kernel(ConvParams p) {
  int gid = blockIdx.x * blockDim.x + threadIdx.x;
  if (gid >= p.total) return;
  int j = 0;
  #pragma unroll
  for (int i = 1; i < 16; i++)
    if (gid >= p.jobs[i].start) j = i;
  ConvJob jb = p.jobs[j];
  int e = gid - jb.start;
  int n = e / jb.Kpad;
  int k = e - n * jb.Kpad;
  float v = (n < jb.N && k < jb.K) ? jb.src[k * jb.N + n] : 0.f;
  p.base[gid] = (f16)v;
}

// ---------------- one MFMA GEMM layer, all n-tiles accumulated concurrently ----
// A frag: m = lane&15 (within wave's 16-row slice), k = (lane>>4)*8 + j
// B frag: n = lane&15, k = (lane>>4)*8 + j   (W stored [n][Kpad] -> contiguous 16B)
// C/D   : col n = lane&15, row m = (lane>>4)*4 + r
template <int KS, int NT, int SS, int DS, bool ACT>
__device__ __forceinline__ void layerT(const f16* src, f16* dst,
                                       const f16* __restrict__ Wt,
                                       const float* __restrict__ bias,
                                       int Nreal, int wave, int lane) {
  constexpr int NTW = NT / 2;
  const int q = lane >> 4, nlo = lane & 15;
  const int mbase = (wave & 1) * 16;
  const int par = wave >> 1;
  const f16* arow = src + (mbase + nlo) * SS + q * 8;
  f32x4 acc[NTW];
  const f16* brow[NTW];
  #pragma unroll
  for (int t = 0; t < NTW; t++) {
    acc[t] = f32x4{0.f, 0.f, 0.f, 0.f};
    brow[t] = Wt + ((par + 2 * t) * 16 + nlo) * (KS * 32) + q * 8;
  }
  #pragma unroll
  for (int k = 0; k < KS; k++) {
    f16x8 a = *(const f16x8*)(arow + k * 32);
    #pragma unroll
    for (int t = 0; t < NTW; t++) {
      f16x8 b = *(const f16x8*)(brow[t] + k * 32);
      acc[t] = __builtin_amdgcn_mfma_f32_16x16x32_f16(a, b, acc[t], 0, 0, 0);
    }
  }
  #pragma unroll
  for (int t = 0; t < NTW; t++) {
    int n = (par + 2 * t) * 16 + nlo;
    float bv = (n < Nreal) ? bias[n] : 0.f;
    #pragma unroll
    for (int r = 0; r < 4; r++) {
      float v = acc[t][r] + bv;
      if (ACT) v = v > 0.f ? v : 0.1f * (__expf(v * 10.f) - 1.f);
      dst[(mbase + q * 4 + r) * DS + n] = (f16)v;
    }
  }
}

// ---------------- fused routed MLP body, 32 atoms per block ----------------
// LDS layout (36 KB -> 4 blocks/CU):
//   X   : [32][392] f16 @ 0        (25088 B)
//   Bf0 : [32][168] f16 @ 25088    (10752 B)
//   Bf1 : [32][136] f16 @ 0        (aliases dead X)
//   idxs: [32] int     @ 35840
template <int NT0, int KS1>
__device__ __forceinline__ void mlp_body(const MlpParams& p, int s, int tile, char* smem) {
  int cnt = p.counts[s];
  if (tile * TM >= cnt) return;
  int valid = min(TM, cnt - tile * TM);
  const int* list = p.lists + s * NATOMS + tile * TM;

  f16* X   = (f16*)smem;
  f16* Bf0 = (f16*)(smem + 25088);
  f16* Bf1 = (f16*)smem;
  int* idxs = (int*)(smem + 35840);

  int t = threadIdx.x;
  if (t < TM) idxs[t] = (t < valid) ? list[t] : -1;

  // gather: 8 threads per atom row, fp32 -> fp16 into LDS
  {
    int row = t >> 3, l8 = t & 7;
    int atom = (row < valid) ? list[row] : -1;
    const float* srcp = p.aev + (size_t)(atom < 0 ? 0 : atom) * 384;
    #pragma unroll
    for (int i = 0; i < 12; i++) {
      int c4 = l8 + i * 8;
      float4 v = make_float4(0.f, 0.f, 0.f, 0.f);
      if (atom >= 0) v = *(const float4*)(srcp + c4 * 4);
      f16x4 h = {(f16)v.x, (f16)v.y, (f16)v.z, (f16)v.w};
      *(f16x4*)(&X[row * 392 + c4 * 4]) = h;
    }
  }
  __syncthreads();

  int wave = t >> 6, lane = t & 63;

  layerT<12, NT0, 392, 168, true>(X, Bf0, p.w[s][0], p.bias[s][0], p.Nreal0[s], wave, lane);
  __syncthreads();
  layerT<KS1, 8, 168, 136, true>(Bf0, Bf1, p.w[s][1], p.bias[s][1], p.Nreal1[s], wave, lane);
  __syncthreads();
  layerT<4, 6, 136, 168, true>(Bf1, Bf0, p.w[s][2], p.bias[s][2], 96, wave, lane);
  __syncthreads();

  // layer 3: K=96, N=1 (W padded to 16 cols, only col 0 nonzero)
  if ((wave >> 1) == 0) {
    int q = lane >> 4, nlo = lane & 15;
    int mbase = (wave & 1) * 16;
    const f16* arow = Bf0 + (mbase + nlo) * 168 + q * 8;
    const f16* brow = p.w[s][3] + nlo * 96 + q * 8;
    f32x4 acc = {0.f, 0.f, 0.f, 0.f};
    #pragma unroll
    for (int k = 0; k < 96; k += 32) {
      f16x8 a = *(const f16x8*)(arow + k);
      f16x8 b = *(const f16x8*)(brow + k);
      acc = __builtin_amdgcn_mfma_f32_16x16x32_f16(a, b, acc, 0, 0, 0);
    }
    if (nlo == 0) {
      float b3 = p.bias[s][3][0];
      float b0v = p.b0[s], b1v = p.b1[s];
      #pragma unroll
      for (int r = 0; r < 4; r++) {
        int m = mbase + q * 4 + r;
        if (m < valid) {
          float coef = acc[r] + b3;
          p.out[idxs[m]] = b0v + b1v * coef;
        }
      }
    }
  }
}

__global__ __launch_bounds__(256, 3) void mlp_kernel(MlpParams p) {
  __shared__ char smem[35968];
  switch (blockIdx.y) {
    case 0: mlp_body<10, 5>(p, 0, blockIdx.x, smem); break;  // H: 384->160->128->96->1
    case 1: mlp_body<10, 5>(p, 1, blockIdx.x, smem); break;  // C: 144 padded to 160
    case 2: mlp_body<8, 4>(p, 2, blockIdx.x, smem); break;   // N: 384->128->112->96->1
    default: mlp_body<8, 4>(p, 3, blockIdx.x, smem); break;  // O
  }
}

extern "C" void kernel_launch(void* const* d_in, const int* in_sizes, int n_in,
                              void* d_out, int out_size, void* d_ws, size_t ws_size,
                              hipStream_t stream) {
  if (ws_size < WS_NEEDED) return;  // workspace too small — fail loud

  const int* species = (const int*)d_in[0];
  const float* aev = (const float*)d_in[1];
  const float* b0 = (const float*)d_in[2];
  const float* b1 = (const float*)d_in[3];

  static const int F1[4]  = {160, 144, 128, 128};
  static const int F1p[4] = {160, 160, 128, 128};
  static const int F2[4]  = {128, 112, 112, 112};

  char* wsb = (char*)d_ws;
  int* counts = (int*)wsb;
  int* lists = (int*)(wsb + WS_LISTS_OFF);
  f16* wbase = (f16*)(wsb + WS_W_OFF);

  ConvParams cp;
  MlpParams mp;
  mp.aev = aev; mp.b0 = b0; mp.b1 = b1;
  mp.counts = counts; mp.lists = lists; mp.out = (float*)d_out;

  int off = 0, ji = 0;
  for (int s = 0; s < 4; s++) {
    int dims[5] = {384, F1[s], F2[s], 96, 1};
    int Kp[4] = {384, F1p[s], 128, 96};
    int Np[4] = {F1p[s], 128, 96, 16};
    for (int l = 0; l < 4; l++) {
      const float* w = (const float*)d_in[4 + s * 8 + l * 2];
      const float* b = (const float*)d_in[4 + s * 8 + l * 2 + 1];
      cp.jobs[ji].src = w;
      cp.jobs[ji].K = dims[l];
      cp.jobs[ji].N = dims[l + 1];
      cp.jobs[ji].Kpad = Kp[l];
      cp.jobs[ji].Npad = Np[l];
      cp.jobs[ji].start = off;
      mp.w[s][l] = wbase + off;
      mp.bias[s][l] = b;
      off += Kp[l] * Np[l];
      ji++;
    }
    mp.Nreal0[s] = F1[s];
    mp.Nreal1[s] = F2[s];
  }
  cp.total = off;
  cp.base = wbase;

  hipMemsetAsync(d_ws, 0, 64, stream);
  route_kernel<<<NATOMS / 256, 256, 0, stream>>>(species, counts, lists);
  convert_kernel<<<(off + 255) / 256, 256, 0, stream>>>(cp);
  mlp_kernel<<<dim3(2048, 4), 256, 0, stream>>>(mp);
}

// Round 3
// 267.689 us; speedup vs baseline: 1.3514x; 1.1750x over previous
//
#include <hip/hip_runtime.h>

typedef _Float16 f16;
typedef _Float16 f16x8 __attribute__((ext_vector_type(8)));
typedef float f32x4 __attribute__((ext_vector_type(4)));
typedef unsigned short u16;

#define NATOMS 65536

// ---------------- workspace layout ----------------
// [0,64)              : counts[4] (zeroed via hipMemsetAsync)
// [256, 256+512K)     : lists u16 [4][65536]
// [524544, +700416)   : fragment-packed fp16 weights (350208 elems)
#define WS_LISTS_OFF 256
#define WS_W_OFF 524544
#define WS_W_ELEMS 350208
#define WS_NEEDED (WS_W_OFF + WS_W_ELEMS * 2)

struct ConvJob { const float* src; int K, N, KS, NT, off; };

struct PrepParams {
  const int* species;
  int* counts;
  u16* lists;
  f16* wbase;
  ConvJob jobs[16];
};

struct MlpParams {
  const float* aev;
  const float* b0;
  const float* b1;
  const float* bias[4][4];
  const f16* w[4][4];       // fragment-packed: [(nt*KS+ks)*64 + lane][8]
  const int* counts;
  const u16* lists;
  float* out;
  int Nreal0[4];            // {160,144,128,128}
  int Nreal1[4];            // {128,112,112,112}
};

// ---------------- prep: routing (blocks 0..255) + weight pack (blocks 256..735) ----
__global__ __launch_bounds__(256) void prep_kernel(PrepParams p) {
  int tid = threadIdx.x;
  if (blockIdx.x < 256) {
    __shared__ int wcnt[4][4];
    __shared__ int wbase[4][4];
    int i = blockIdx.x * 256 + tid;
    int s = p.species[i];
    int wave = tid >> 6, lane = tid & 63;
    unsigned long long m[4];
    #pragma unroll
    for (int t = 0; t < 4; t++) {
      m[t] = __ballot(s == t);
      if (lane == 0) wcnt[wave][t] = __popcll(m[t]);
    }
    __syncthreads();
    if (tid < 4) {
      int t = tid;
      int c0 = wcnt[0][t], c1 = wcnt[1][t], c2 = wcnt[2][t], c3 = wcnt[3][t];
      int base = atomicAdd(&p.counts[t], c0 + c1 + c2 + c3);
      wbase[0][t] = base;
      wbase[1][t] = base + c0;
      wbase[2][t] = base + c0 + c1;
      wbase[3][t] = base + c0 + c1 + c2;
    }
    __syncthreads();
    int rnk = __popcll(m[s] & ((1ull << lane) - 1ull));
    p.lists[s * NATOMS + wbase[wave][s] + rnk] = (u16)i;
  } else {
    // weight conversion: fp32 [K][N] -> fp16 fragment-packed, zero-padded
    int bx = blockIdx.x - 256;
    int job = bx / 30, bxin = bx - job * 30;
    ConvJob jb = p.jobs[job];
    int fid = bxin * 256 + tid;
    int nfrag = jb.KS * jb.NT * 64;
    if (fid >= nfrag) return;
    int ks64 = jb.KS * 64;
    int nt = fid / ks64;
    int rem = fid - nt * ks64;
    int ks = rem >> 6, lane = rem & 63;
    int q = lane >> 4, nlo = lane & 15;
    int n = nt * 16 + nlo;
    int k0 = ks * 32 + q * 8;
    f16x8 v;
    #pragma unroll
    for (int j = 0; j < 8; j++) {
      int k = k0 + j;
      float x = (n < jb.N && k < jb.K) ? jb.src[k * jb.N + n] : 0.f;
      v[j] = (f16)x;
    }
    *(f16x8*)(p.wbase + jb.off + (size_t)fid * 8) = v;
  }
}

__device__ __forceinline__ float celu01(float v) {
  return v > 0.f ? v : 0.1f * (__expf(v * 10.f) - 1.f);
}

// One GEMM layer for one wave's 16 atoms. A in registers, B fragment-packed
// from global (L1/L2-hot), epilogue bias+CELU -> wave-private LDS rows.
// A frag: m=lane&15, k=q*8+j within ks-block. C/D: n=lane&15, m=q*4+r.
template <int KS, int NT>
__device__ __forceinline__ void gemm_layer(const f16x8* a, const f16* __restrict__ Wt,
                                           const float* __restrict__ bias, int Nreal,
                                           f16* dstw, int DS, int q, int nlo, int lane) {
  #pragma unroll
  for (int pp = 0; pp < NT / 2; pp++) {
    const f16* bp0 = Wt + (size_t)((2 * pp) * KS * 64 + lane) * 8;
    const f16* bp1 = Wt + (size_t)((2 * pp + 1) * KS * 64 + lane) * 8;
    f32x4 acc0 = {0.f, 0.f, 0.f, 0.f};
    f32x4 acc1 = {0.f, 0.f, 0.f, 0.f};
    #pragma unroll
    for (int ks = 0; ks < KS; ks++) {
      f16x8 b0 = *(const f16x8*)(bp0 + ks * 512);
      f16x8 b1 = *(const f16x8*)(bp1 + ks * 512);
      acc0 = __builtin_amdgcn_mfma_f32_16x16x32_f16(a[ks], b0, acc0, 0, 0, 0);
      acc1 = __builtin_amdgcn_mfma_f32_16x16x32_f16(a[ks], b1, acc1, 0, 0, 0);
    }
    #pragma unroll
    for (int h = 0; h < 2; h++) {
      int n = (2 * pp + h) * 16 + nlo;
      float bv = (n < Nreal) ? bias[n] : 0.f;
      f32x4 ac = h ? acc1 : acc0;
      #pragma unroll
      for (int r = 0; r < 4; r++) {
        float v = celu01(ac[r] + bv);
        dstw[(q * 4 + r) * DS + n] = (f16)v;
      }
    }
  }
}

// ---------------- fused routed MLP: 64 atoms/block, wave owns 16, no barriers ----
template <int NT0, int KS1>
__device__ __forceinline__ void mlp_body(const MlpParams& p, int s, int tile,
                                         f16* Bf0, f16* Bf1) {
  int cnt = p.counts[s];
  if (tile * 64 >= cnt) return;
  const u16* list = p.lists + s * NATOMS;
  int tid = threadIdx.x, w = tid >> 6, lane = tid & 63;
  int q = lane >> 4, nlo = lane & 15;
  int rowbase = tile * 64 + w * 16;

  int rr = rowbase + nlo;
  int atom = list[min(rr, cnt - 1)];

  // layer-0 A: direct global fp32 -> fp16 fragments (row read once, coalesced 16B)
  f16x8 a0[12];
  const float* ap = p.aev + (size_t)atom * 384 + q * 8;
  #pragma unroll
  for (int ks = 0; ks < 12; ks++) {
    float4 u0 = *(const float4*)(ap + ks * 32);
    float4 u1 = *(const float4*)(ap + ks * 32 + 4);
    f16x8 t = {(f16)u0.x, (f16)u0.y, (f16)u0.z, (f16)u0.w,
               (f16)u1.x, (f16)u1.y, (f16)u1.z, (f16)u1.w};
    a0[ks] = t;
  }

  f16* my0 = Bf0 + (w * 16) * 168;  // wave-private 16 rows, stride 168
  f16* my1 = Bf1 + (w * 16) * 136;

  gemm_layer<12, NT0>(a0, p.w[s][0], p.bias[s][0], p.Nreal0[s], my0, 168, q, nlo, lane);

  f16x8 a1[KS1];
  #pragma unroll
  for (int ks = 0; ks < KS1; ks++)
    a1[ks] = *(const f16x8*)(my0 + nlo * 168 + ks * 32 + q * 8);
  gemm_layer<KS1, 8>(a1, p.w[s][1], p.bias[s][1], p.Nreal1[s], my1, 136, q, nlo, lane);

  f16x8 a2[4];
  #pragma unroll
  for (int ks = 0; ks < 4; ks++)
    a2[ks] = *(const f16x8*)(my1 + nlo * 136 + ks * 32 + q * 8);
  gemm_layer<4, 6>(a2, p.w[s][2], p.bias[s][2], 96, my0, 168, q, nlo, lane);

  // layer 3: K=96, N=1 (packed with NT=1, cols 1..15 zero)
  f16x8 a3[3];
  #pragma unroll
  for (int ks = 0; ks < 3; ks++)
    a3[ks] = *(const f16x8*)(my0 + nlo * 168 + ks * 32 + q * 8);
  f32x4 acc = {0.f, 0.f, 0.f, 0.f};
  const f16* W3 = p.w[s][3];
  #pragma unroll
  for (int ks = 0; ks < 3; ks++) {
    f16x8 b = *(const f16x8*)(W3 + (size_t)(ks * 64 + lane) * 8);
    acc = __builtin_amdgcn_mfma_f32_16x16x32_f16(a3[ks], b, acc, 0, 0, 0);
  }
  if (nlo == 0) {
    float b3 = p.bias[s][3][0];
    float b0v = p.b0[s], b1v = p.b1[s];
    #pragma unroll
    for (int r = 0; r < 4; r++) {
      int m = rowbase + q * 4 + r;
      if (m < cnt) {
        float coef = acc[r] + b3;
        p.out[list[m]] = b0v + b1v * coef;
      }
    }
  }
}

__global__ __launch_bounds__(256) void mlp_kernel(MlpParams p) {
  __shared__ f16 Bf0[64 * 168];  // 21504 B
  __shared__ f16 Bf1[64 * 136];  // 17408 B
  switch (blockIdx.y) {
    case 0: mlp_body<10, 5>(p, 0, blockIdx.x, Bf0, Bf1); break;  // H 384->160->128->96->1
    case 1: mlp_body<10, 5>(p, 1, blockIdx.x, Bf0, Bf1); break;  // C (144 pad 160)
    case 2: mlp_body<8, 4>(p, 2, blockIdx.x, Bf0, Bf1); break;   // N 384->128->112->96->1
    default: mlp_body<8, 4>(p, 3, blockIdx.x, Bf0, Bf1); break;  // O
  }
}

extern "C" void kernel_launch(void* const* d_in, const int* in_sizes, int n_in,
                              void* d_out, int out_size, void* d_ws, size_t ws_size,
                              hipStream_t stream) {
  if (ws_size < WS_NEEDED) return;  // workspace too small — fail loud

  const int* species = (const int*)d_in[0];
  const float* aev = (const float*)d_in[1];
  const float* b0 = (const float*)d_in[2];
  const float* b1 = (const float*)d_in[3];

  static const int F1[4]  = {160, 144, 128, 128};
  static const int F1p[4] = {160, 160, 128, 128};
  static const int F2[4]  = {128, 112, 112, 112};

  char* wsb = (char*)d_ws;
  int* counts = (int*)wsb;
  u16* lists = (u16*)(wsb + WS_LISTS_OFF);
  f16* wbase = (f16*)(wsb + WS_W_OFF);

  PrepParams pp;
  pp.species = species; pp.counts = counts; pp.lists = lists; pp.wbase = wbase;

  MlpParams mp;
  mp.aev = aev; mp.b0 = b0; mp.b1 = b1;
  mp.counts = counts; mp.lists = lists; mp.out = (float*)d_out;

  int off = 0, ji = 0;
  for (int s = 0; s < 4; s++) {
    int K[4]  = {384, F1[s], F2[s], 96};
    int N[4]  = {F1[s], F2[s], 96, 1};
    int KS[4] = {12, F1p[s] / 32, 4, 3};
    int NT[4] = {F1p[s] / 16, 8, 6, 1};
    for (int l = 0; l < 4; l++) {
      const float* w = (const float*)d_in[4 + s * 8 + l * 2];
      const float* b = (const float*)d_in[4 + s * 8 + l * 2 + 1];
      pp.jobs[ji].src = w;
      pp.jobs[ji].K = K[l];
      pp.jobs[ji].N = N[l];
      pp.jobs[ji].KS = KS[l];
      pp.jobs[ji].NT = NT[l];
      pp.jobs[ji].off = off;
      mp.w[s][l] = wbase + off;
      mp.bias[s][l] = b;
      off += KS[l] * NT[l] * 512;
      ji++;
    }
    mp.Nreal0[s] = F1[s];
    mp.Nreal1[s] = F2[s];
  }

  hipMemsetAsync(d_ws, 0, 64, stream);
  prep_kernel<<<dim3(256 + 480), 256, 0, stream>>>(pp);
  mlp_kernel<<<dim3(1024, 4), 256, 0, stream>>>(mp);
}

// Round 5
// 264.530 us; speedup vs baseline: 1.3676x; 1.0119x over previous
//
#include <hip/hip_runtime.h>

typedef _Float16 f16;
typedef _Float16 f16x8 __attribute__((ext_vector_type(8)));
typedef float f32x4 __attribute__((ext_vector_type(4)));
typedef unsigned short u16;

#define NATOMS 65536

// ---------------- workspace layout ----------------
// [0,64)              : counts[4] (zeroed via hipMemsetAsync)
// [256, 256+512K)     : lists u16 [4][65536]
// [524544, +700416)   : fragment-packed fp16 weights (350208 elems)
#define WS_LISTS_OFF 256
#define WS_W_OFF 524544
#define WS_W_ELEMS 350208
#define WS_NEEDED (WS_W_OFF + WS_W_ELEMS * 2)

struct ConvJob { const float* src; int K, N, KS, NT, off; };

struct PrepParams {
  const int* species;
  int* counts;
  u16* lists;
  f16* wbase;
  ConvJob jobs[16];
};

struct MlpParams {
  const float* aev;
  const float* b0;
  const float* b1;
  const float* bias[4][4];
  const f16* w[4][4];       // fragment-packed: [(nt*KS+ks)*64 + lane][8]
  const int* counts;
  const u16* lists;
  float* out;
  int Nreal0[4];            // {160,144,128,128}
  int Nreal1[4];            // {128,112,112,112}
};

// ---------------- prep: routing (blocks 0..255) + weight pack (blocks 256..735) ----
__global__ __launch_bounds__(256) void prep_kernel(PrepParams p) {
  int tid = threadIdx.x;
  if (blockIdx.x < 256) {
    __shared__ int wcnt[4][4];
    __shared__ int wbase[4][4];
    int i = blockIdx.x * 256 + tid;
    int s = p.species[i];
    int wave = tid >> 6, lane = tid & 63;
    unsigned long long m[4];
    #pragma unroll
    for (int t = 0; t < 4; t++) {
      m[t] = __ballot(s == t);
      if (lane == 0) wcnt[wave][t] = __popcll(m[t]);
    }
    __syncthreads();
    if (tid < 4) {
      int t = tid;
      int c0 = wcnt[0][t], c1 = wcnt[1][t], c2 = wcnt[2][t], c3 = wcnt[3][t];
      int base = atomicAdd(&p.counts[t], c0 + c1 + c2 + c3);
      wbase[0][t] = base;
      wbase[1][t] = base + c0;
      wbase[2][t] = base + c0 + c1;
      wbase[3][t] = base + c0 + c1 + c2;
    }
    __syncthreads();
    int rnk = __popcll(m[s] & ((1ull << lane) - 1ull));
    p.lists[s * NATOMS + wbase[wave][s] + rnk] = (u16)i;
  } else {
    // weight conversion: fp32 [K][N] -> fp16 fragment-packed, zero-padded
    int bx = blockIdx.x - 256;
    int job = bx / 30, bxin = bx - job * 30;
    ConvJob jb = p.jobs[job];
    int fid = bxin * 256 + tid;
    int nfrag = jb.KS * jb.NT * 64;
    if (fid >= nfrag) return;
    int ks64 = jb.KS * 64;
    int nt = fid / ks64;
    int rem = fid - nt * ks64;
    int ks = rem >> 6, lane = rem & 63;
    int q = lane >> 4, nlo = lane & 15;
    int n = nt * 16 + nlo;
    int k0 = ks * 32 + q * 8;
    f16x8 v;
    #pragma unroll
    for (int j = 0; j < 8; j++) {
      int k = k0 + j;
      float x = (n < jb.N && k < jb.K) ? jb.src[k * jb.N + n] : 0.f;
      v[j] = (f16)x;
    }
    *(f16x8*)(p.wbase + jb.off + (size_t)fid * 8) = v;
  }
}

__device__ __forceinline__ float celu01(float v) {
  return v > 0.f ? v : 0.1f * (__expf(v * 10.f) - 1.f);
}

// stage one 1KB fragment (64 lanes x 16B) global -> LDS (lds dest wave-uniform)
__device__ __forceinline__ void stage_frag(const f16* g, f16* l, int lane) {
  __builtin_amdgcn_global_load_lds(
      (const __attribute__((address_space(1))) unsigned int*)(g + lane * 8),
      (__attribute__((address_space(3))) unsigned int*)l, 16, 0, 0);
}

// ---------------- one GEMM layer, B staged block-wide through a 3-slot LDS ring ----
// Chunks of <=4 k-frags (4KB). Wave w stages fragment w of the chunk into
// slot_base + w*512 elems (matches consumer layout: fragment j at j*1024 B).
// 1 barrier per chunk; all 4 waves consume the same B chunk (LDS broadcast),
// each wave owns 16 atom rows (wave-private A regs + activation LDS slice).
template <int KS, int NT, bool ACT>
__device__ __forceinline__ int layer_lds(const f16x8* a, const f16* __restrict__ Wt,
                                         const float* __restrict__ bias, int Nreal,
                                         f16* dstw, int DS, f16* ring, int r0,
                                         int w, int lane, int q, int nlo) {
  constexpr int SUBS = (KS + 3) / 4;
  constexpr int C = NT * SUBS;
  {
    constexpr int nks0 = (KS < 4) ? KS : 4;
    if (w < nks0)
      stage_frag(Wt + (size_t)w * 512,
                 ring + (size_t)(r0 % 3) * 2048 + w * 512, lane);
  }
  f32x4 acc = {0.f, 0.f, 0.f, 0.f};
  #pragma unroll
  for (int c = 0; c < C; c++) {
    if (c + 1 < C) {
      int nt1 = (c + 1) / SUBS, sub1 = (c + 1) % SUBS;
      int k01 = sub1 * 4;
      int nks1 = (KS - k01 < 4) ? (KS - k01) : 4;
      if (w < nks1)
        stage_frag(Wt + (size_t)(nt1 * KS + k01 + w) * 512,
                   ring + (size_t)((r0 + c + 1) % 3) * 2048 + w * 512, lane);
    }
    __syncthreads();
    int nt = c / SUBS, sub = c % SUBS;
    int k0 = sub * 4;
    int nks = (KS - k0 < 4) ? (KS - k0) : 4;
    const f16* slot = ring + (size_t)((r0 + c) % 3) * 2048;
    if (sub == 0) acc = f32x4{0.f, 0.f, 0.f, 0.f};
    #pragma unroll
    for (int j = 0; j < 4; j++) {
      if (j < nks) {
        f16x8 b = *(const f16x8*)(slot + (j * 64 + lane) * 8);
        acc = __builtin_amdgcn_mfma_f32_16x16x32_f16(a[k0 + j], b, acc, 0, 0, 0);
      }
    }
    if (sub == SUBS - 1) {
      int n = nt * 16 + nlo;
      float bv = (n < Nreal) ? bias[n] : 0.f;
      #pragma unroll
      for (int r = 0; r < 4; r++) {
        float v = acc[r] + bv;
        if (ACT) v = celu01(v);
        dstw[(q * 4 + r) * DS + n] = (f16)v;
      }
    }
  }
  return (r0 + C) % 3;
}

// ---------------- fused routed MLP: 64 atoms/block, wave owns 16 ----
template <int NT0, int KS1>
__device__ __forceinline__ void mlp_body(const MlpParams& p, int s, int tile,
                                         f16* ring, f16* Bf0, f16* Bf1) {
  int cnt = p.counts[s];
  if (tile * 64 >= cnt) return;
  const u16* list = p.lists + s * NATOMS;
  int tid = threadIdx.x, w = tid >> 6, lane = tid & 63;
  int q = lane >> 4, nlo = lane & 15;
  int rowbase = tile * 64 + w * 16;

  int rr = rowbase + nlo;
  int atom = list[min(rr, cnt - 1)];

  // layer-0 A: direct global fp32 -> fp16 fragments (issued before staging so
  // HBM latency overlaps the first B chunks)
  f16x8 a0[12];
  const float* ap = p.aev + (size_t)atom * 384 + q * 8;
  #pragma unroll
  for (int ks = 0; ks < 12; ks++) {
    float4 u0 = *(const float4*)(ap + ks * 32);
    float4 u1 = *(const float4*)(ap + ks * 32 + 4);
    f16x8 t = {(f16)u0.x, (f16)u0.y, (f16)u0.z, (f16)u0.w,
               (f16)u1.x, (f16)u1.y, (f16)u1.z, (f16)u1.w};
    a0[ks] = t;
  }

  f16* my0 = Bf0 + (w * 16) * 168;  // wave-private 16 rows, stride 168
  f16* my1 = Bf1 + (w * 16) * 136;

  int r0 = 0;
  r0 = layer_lds<12, NT0, true>(a0, p.w[s][0], p.bias[s][0], p.Nreal0[s],
                                my0, 168, ring, r0, w, lane, q, nlo);

  f16x8 a1[KS1];
  #pragma unroll
  for (int ks = 0; ks < KS1; ks++)
    a1[ks] = *(const f16x8*)(my0 + nlo * 168 + ks * 32 + q * 8);
  r0 = layer_lds<KS1, 8, true>(a1, p.w[s][1], p.bias[s][1], p.Nreal1[s],
                               my1, 136, ring, r0, w, lane, q, nlo);

  f16x8 a2[4];
  #pragma unroll
  for (int ks = 0; ks < 4; ks++)
    a2[ks] = *(const f16x8*)(my1 + nlo * 136 + ks * 32 + q * 8);
  r0 = layer_lds<4, 6, true>(a2, p.w[s][2], p.bias[s][2], 96,
                             my0, 168, ring, r0, w, lane, q, nlo);

  // layer 3: K=96, N=1, register path (3KB, L2-hot)
  f16x8 a3[3];
  #pragma unroll
  for (int ks = 0; ks < 3; ks++)
    a3[ks] = *(const f16x8*)(my0 + nlo * 168 + ks * 32 + q * 8);
  f32x4 acc = {0.f, 0.f, 0.f, 0.f};
  const f16* W3 = p.w[s][3];
  #pragma unroll
  for (int ks = 0; ks < 3; ks++) {
    f16x8 b = *(const f16x8*)(W3 + (size_t)(ks * 64 + lane) * 8);
    acc = __builtin_amdgcn_mfma_f32_16x16x32_f16(a3[ks], b, acc, 0, 0, 0);
  }
  if (nlo == 0) {
    float b3 = p.bias[s][3][0];
    float b0v = p.b0[s], b1v = p.b1[s];
    #pragma unroll
    for (int r = 0; r < 4; r++) {
      int m = rowbase + q * 4 + r;
      if (m < cnt) {
        float coef = acc[r] + b3;
        p.out[list[m]] = b0v + b1v * coef;
      }
    }
  }
}

// LDS: ring 3*4KB = 12288B, Bf0 21504B, Bf1 17408B -> 51200B -> 3 blocks/CU
__global__ __launch_bounds__(256, 3) void mlp_kernel(MlpParams p) {
  __shared__ f16 ring[3 * 2048];
  __shared__ f16 Bf0[64 * 168];
  __shared__ f16 Bf1[64 * 136];
  int s = blockIdx.x & 3;        // species fastest: same-species blocks co-resident per CU
  int tile = blockIdx.x >> 2;
  switch (s) {
    case 0: mlp_body<10, 5>(p, 0, tile, ring, Bf0, Bf1); break;  // H 384->160->128->96->1
    case 1: mlp_body<10, 5>(p, 1, tile, ring, Bf0, Bf1); break;  // C (144 pad 160)
    case 2: mlp_body<8, 4>(p, 2, tile, ring, Bf0, Bf1); break;   // N 384->128->112->96->1
    default: mlp_body<8, 4>(p, 3, tile, ring, Bf0, Bf1); break;  // O
  }
}

extern "C" void kernel_launch(void* const* d_in, const int* in_sizes, int n_in,
                              void* d_out, int out_size, void* d_ws, size_t ws_size,
                              hipStream_t stream) {
  if (ws_size < WS_NEEDED) return;  // workspace too small — fail loud

  const int* species = (const int*)d_in[0];
  const float* aev = (const float*)d_in[1];
  const float* b0 = (const float*)d_in[2];
  const float* b1 = (const float*)d_in[3];

  static const int F1[4]  = {160, 144, 128, 128};
  static const int F1p[4] = {160, 160, 128, 128};
  static const int F2[4]  = {128, 112, 112, 112};

  char* wsb = (char*)d_ws;
  int* counts = (int*)wsb;
  u16* lists = (u16*)(wsb + WS_LISTS_OFF);
  f16* wbase = (f16*)(wsb + WS_W_OFF);

  PrepParams pp;
  pp.species = species; pp.counts = counts; pp.lists = lists; pp.wbase = wbase;

  MlpParams mp;
  mp.aev = aev; mp.b0 = b0; mp.b1 = b1;
  mp.counts = counts; mp.lists = lists; mp.out = (float*)d_out;

  int off = 0, ji = 0;
  for (int s = 0; s < 4; s++) {
    int K[4]  = {384, F1[s], F2[s], 96};
    int N[4]  = {F1[s], F2[s], 96, 1};
    int KS[4] = {12, F1p[s] / 32, 4, 3};
    int NT[4] = {F1p[s] / 16, 8, 6, 1};
    for (int l = 0; l < 4; l++) {
      const float* w = (const float*)d_in[4 + s * 8 + l * 2];
      const float* b = (const float*)d_in[4 + s * 8 + l * 2 + 1];
      pp.jobs[ji].src = w;
      pp.jobs[ji].K = K[l];
      pp.jobs[ji].N = N[l];
      pp.jobs[ji].KS = KS[l];
      pp.jobs[ji].NT = NT[l];
      pp.jobs[ji].off = off;
      mp.w[s][l] = wbase + off;
      mp.bias[s][l] = b;
      off += KS[l] * NT[l] * 512;
      ji++;
    }
    mp.Nreal0[s] = F1[s];
    mp.Nreal1[s] = F2[s];
  }

  hipMemsetAsync(d_ws, 0, 64, stream);
  prep_kernel<<<dim3(256 + 480), 256, 0, stream>>>(pp);
  // 280 tiles/species (17920 atoms headroom vs ~16384 expected +14 sigma)
  mlp_kernel<<<dim3(280 * 4), 256, 0, stream>>>(mp);
}